// Round 12
// baseline (169.722 us; speedup 1.0000x reference)
//
#include <hip/hip_runtime.h>

typedef __attribute__((ext_vector_type(8))) short short8;
typedef __attribute__((ext_vector_type(4))) float f32x4;

#define NODAL_ELEMS 21233664     // 8*8*144*144*16
#define BSLAB 81920              // 640*128 elements per direction
#define NB_OFF 327680            // byte offset of bf16 nodal in ws (2*BSLAB*2)
#define C0_OFF (NB_OFF + (size_t)NODAL_ELEMS * 2)   // bf16 C0 partial (frag order)

__device__ __forceinline__ unsigned short f2bf(float f) {
    unsigned int u = __float_as_uint(f);
    u += 0x7FFFu + ((u >> 16) & 1u);     // RNE
    return (unsigned short)(u >> 16);
}
__device__ __forceinline__ float bf2f(unsigned short s) {
    return __uint_as_float(((unsigned int)s) << 16);
}

__device__ __forceinline__ void gload_lds16(const void* g, void* l) {
    __builtin_amdgcn_global_load_lds(
        (const __attribute__((address_space(1))) unsigned int*)g,
        (__attribute__((address_space(3))) unsigned int*)l, 16, 0, 0);
}

// ---------------------------------------------------------------------------
// Build B matrices in fragment-order layout: B[d][kk=K/8][n=0..127][j=K%8]
// ---------------------------------------------------------------------------
__global__ void build_b_kernel(const float* __restrict__ coef0,
                               const float* __restrict__ coef1,
                               const float* __restrict__ ws0,
                               const float* __restrict__ ws1,
                               const float* __restrict__ grid,
                               unsigned short* __restrict__ B)
{
    const int bid = blockIdx.x;
    const int d   = (bid >= 320) ? 1 : 0;
    const int rem = bid - d * 320;
    const int k   = rem >> 6;
    const int X   = (rem >> 3) & 7;
    const int x   = rem & 7;

    const float* __restrict__ coef = d ? coef1 : coef0;
    const float* __restrict__ ws   = d ? ws1 : ws0;
    unsigned short* __restrict__ Bd = B + d * BSLAB;

    const float xy = (grid[X] - (grid[x] + (float)(k - 2))) * 0.25f;
    const int t = threadIdx.x;          // i*16 + o
    const int i = t >> 4;
    const int o = t & 15;

    float acc = 0.f;
    #pragma unroll 1
    for (int j = 0; j < 33; ++j) {
        float ang = 6.283185307179586f * (float)j * xy;
        float c = cosf(ang);
        float s = sinf(ang);
        float sc = (j == 0 || j == 32) ? 1.f : 2.f;
        float rr = coef[j * 256 + t];
        float ii = (j >= 1 && j <= 31) ? coef[(64 - j) * 256 + t] : 0.f;
        acc += sc * (c * rr - s * ii);
    }
    float val = acc * ws[(k * 8 + X) * 8 + x];

    const int kk = k * 16 + x * 2 + (i >> 3);
    const int jj = i & 7;
    const int n  = X * 16 + o;
    Bd[(kk * 128 + n) * 8 + jj] = f2bf(val);
}

// ---------------------------------------------------------------------------
// nodal fp32 -> bf16
// ---------------------------------------------------------------------------
__global__ void cvt_kernel(const float* __restrict__ in,
                           unsigned short* __restrict__ out, int n4)
{
    int idx = blockIdx.x * blockDim.x + threadIdx.x;
    int stride = gridDim.x * blockDim.x;
    for (int j = idx; j < n4; j += stride) {
        float4 v = ((const float4*)in)[j];
        ushort4 r;
        r.x = f2bf(v.x); r.y = f2bf(v.y); r.z = f2bf(v.z); r.w = f2bf(v.w);
        ((ushort4*)out)[j] = r;
    }
}

// ---------------------------------------------------------------------------
// MFMA conv kernel. TERM=0: fixed q, contract (k,x,i); writes C0 in
// accumulator-FRAGMENT order keyed by (rest,w,mf,p,q,lane). TERM=1: fixed p,
// contract (k,y,i); adds C0 + writes fp32 out (or RMW fp32 fallback).
// Block: 256 thr (4 waves). Per TILE: M=128 (wave M32xN128), N=128, K=640.
// Each block processes BOTH b-halves (tile 0: half 0, tile 1: half 1, same
// mt) sequentially -> grid 648 (one resident batch), tile-1 A/B are L2-hot.
// K-loop: 10 chunks of 2 K-steps. Depth-2 pipeline: B staged into a 3x16KB
// LDS ring via global_load_lds 2 chunks ahead; A reg-prefetched 2 chunks
// ahead. Barrier = counted s_waitcnt vmcnt + raw s_barrier (no drain).
// Raw s_barrier between tiles protects the LDS ring WAR.
// Grid 648 1-D, XCD-pinned (XF=bid&7).
// ---------------------------------------------------------------------------
template<int TERM, bool AB16, bool C0B16>
__global__ __launch_bounds__(256, 3)
void conv_mfma(const float* __restrict__ nodalf,
               const unsigned short* __restrict__ nodalb,
               const unsigned short* __restrict__ Bmat,
               unsigned short* __restrict__ c0,
               float* __restrict__ out)
{
    __shared__ __align__(16) char lds[3][16384];   // 3 x 16KB B-chunk ring

    const int tid = threadIdx.x;
    const int w   = tid >> 6;
    const int l   = tid & 63;
    const int sub = l >> 4;
    const int lr  = l & 15;

    const int bid = blockIdx.x;
    const int XF  = bid & 7;            // q (TERM0) / p (TERM1) -> per-XCD slab
    const int gg  = bid >> 3;           // 0..80 (mt)

    const int scal = (TERM == 0) ? XF * 331776 : XF * 2654208;
    const int KSTR = (TERM == 0) ? 2654208 : 331776;   // x / y stride (elems)

    const unsigned short* nb = nodalb + scal;
    const float* nfp = nodalf + scal;
    const char* Bb = (const char*)Bmat;
    const int rowbase = gg * 128 + w * 32;

#define STAGE_B(buf_, c_) do {                                               \
    _Pragma("unroll")                                                        \
    for (int u_ = 0; u_ < 4; ++u_)                                           \
        gload_lds16(Bb + (c_) * 16384 + u_ * 4096 + tid * 16,                \
                    &lds[buf_][u_ * 4096 + tid * 16]);                       \
} while (0)

#define LOAD_A(slot_, c_) do {                                               \
    _Pragma("unroll")                                                        \
    for (int ksp_ = 0; ksp_ < 2; ++ksp_) {                                   \
        const int ks_ = 2 * (c_) + ksp_;                                     \
        _Pragma("unroll")                                                    \
        for (int mf_ = 0; mf_ < 2; ++mf_) {                                  \
            if (AB16) {                                                      \
                Ab[slot_][ksp_][mf_] = *(const short8*)                      \
                    (nb + base[mf_][ks_ >> 2] + (ks_ & 3) * 2 * KSTR);       \
            } else {                                                         \
                const float* s_ = nfp + base[mf_][ks_ >> 2]                  \
                                      + (ks_ & 3) * 2 * KSTR;                \
                Af[slot_][ksp_][mf_][0] = *(const float4*)s_;                \
                Af[slot_][ksp_][mf_][1] = *(const float4*)(s_ + 4);          \
            }                                                                \
        }                                                                    \
    } } while (0)

#define CHUNK_BARRIER(vm_) do {                                              \
    __builtin_amdgcn_sched_barrier(0);                                       \
    asm volatile("s_waitcnt vmcnt(" vm_ ")" ::: "memory");                   \
    __builtin_amdgcn_s_barrier();                                            \
    __builtin_amdgcn_sched_barrier(0);                                       \
} while (0)

    #pragma unroll 1
    for (int tile = 0; tile < 2; ++tile) {
        const int half = tile;
        const int rest = tile * 81 + gg;     // C0 key index (0..161)

        // per-lane per-tap base element offsets (incl. lane K-sub placement)
        int base[2][5];
        #pragma unroll
        for (int mf = 0; mf < 2; ++mf) {
            int row = rowbase + mf * 16 + lr;      // 0..10367
            int a = row / 72;
            int b = row - a * 72 + half * 72;
            #pragma unroll
            for (int k = 0; k < 5; ++k) {
                int sh = ((TERM == 0) ? a : b) + k - 2;
                if (sh < 0) sh += 144;
                if (sh >= 144) sh -= 144;
                int off = (TERM == 0) ? (sh * 2304 + b * 16)
                                      : (a * 2304 + sh * 16);
                base[mf][k] = off + (sub >> 1) * KSTR + (sub & 1) * 8;
            }
        }

        f32x4 acc[2][8];
        #pragma unroll
        for (int mf = 0; mf < 2; ++mf)
            #pragma unroll
            for (int nf = 0; nf < 8; ++nf)
                acc[mf][nf] = (f32x4){0.f, 0.f, 0.f, 0.f};

        short8 Ab[3][2][2];        // [slot][ksp][mf] bf16 path
        float4 Af[3][2][2][2];     // fp32 fallback path

        if (tile) {
            // WAR guard: all waves' tile-0 LDS reads complete before their
            // final MFMAs, hence before this barrier; DMA below is safe.
            __builtin_amdgcn_sched_barrier(0);
            __builtin_amdgcn_s_barrier();
            __builtin_amdgcn_sched_barrier(0);
        }

        // prologue: stage chunks 0,1 ; A-load chunks 0,1
        STAGE_B(0, 0);
        STAGE_B(1, 1);
        __builtin_amdgcn_sched_barrier(0);
        LOAD_A(0, 0);
        LOAD_A(1, 1);
        CHUNK_BARRIER("8");     // retires S0,S1 (A0/A1 waited by use-deps)

        #pragma unroll
        for (int c = 0; c < 10; ++c) {
            if (c < 8) {
                STAGE_B((c + 2) % 3, c + 2);
                __builtin_amdgcn_sched_barrier(0);
                LOAD_A((c + 2) % 3, c + 2);
                __builtin_amdgcn_sched_barrier(0);
            }

            #pragma unroll
            for (int ksp = 0; ksp < 2; ++ksp) {
                short8 a0, a1;
                if (AB16) {
                    a0 = Ab[c % 3][ksp][0];
                    a1 = Ab[c % 3][ksp][1];
                } else {
                    #pragma unroll
                    for (int e = 0; e < 4; ++e) {
                        a0[e]     = (short)f2bf(((const float*)&Af[c % 3][ksp][0][0])[e]);
                        a0[e + 4] = (short)f2bf(((const float*)&Af[c % 3][ksp][0][1])[e]);
                        a1[e]     = (short)f2bf(((const float*)&Af[c % 3][ksp][1][0])[e]);
                        a1[e + 4] = (short)f2bf(((const float*)&Af[c % 3][ksp][1][1])[e]);
                    }
                }

                const char* bbase = lds[c % 3] + ksp * 8192 + sub * 2048 + lr * 16;
                #pragma unroll
                for (int nf = 0; nf < 8; ++nf) {
                    short8 bf = *(const short8*)(bbase + nf * 256);
                    acc[0][nf] = __builtin_amdgcn_mfma_f32_16x16x32_bf16(
                        a0, bf, acc[0][nf], 0, 0, 0);
                    acc[1][nf] = __builtin_amdgcn_mfma_f32_16x16x32_bf16(
                        a1, bf, acc[1][nf], 0, 0, 0);
                }
            }

            if (c < 9) {
                if (c == 8) CHUNK_BARRIER("4");   // newest 4 = A(9); S(9) retired
                else        CHUNK_BARRIER("8");
            }
        }

        // ---- epilogue ----
        if (C0B16) {
            // C0 fragment key symmetric in (p,q): frag(rest,w,mf,p,q)
            // TERM0: p = nf, q = XF.  TERM1: p = XF, q = nf.
            #pragma unroll
            for (int mf = 0; mf < 2; ++mf) {
                #pragma unroll
                for (int nf = 0; nf < 8; ++nf) {
                    const int P = (TERM == 0) ? nf : XF;
                    const int Q = (TERM == 0) ? XF : nf;
                    unsigned short* cp = c0 +
                        (((((size_t)rest * 4 + w) * 2 + mf) * 8 + P) * 8 + Q) * 256
                        + l * 4;
                    if (TERM == 0) {
                        ushort4 cs;
                        cs.x = f2bf(acc[mf][nf][0]);
                        cs.y = f2bf(acc[mf][nf][1]);
                        cs.z = f2bf(acc[mf][nf][2]);
                        cs.w = f2bf(acc[mf][nf][3]);
                        *(ushort4*)cp = cs;
                    } else {
                        ushort4 cv = *(const ushort4*)cp;
                        unsigned short ca[4] = {cv.x, cv.y, cv.z, cv.w};
                        #pragma unroll
                        for (int r = 0; r < 4; ++r) {
                            int row = rowbase + mf * 16 + sub * 4 + r;
                            int a = row / 72;
                            int b = row - a * 72 + half * 72;
                            int idx = XF * 2654208 + nf * 331776 +
                                      (a * 144 + b) * 16 + lr;
                            out[idx] = acc[mf][nf][r] + bf2f(ca[r]);
                        }
                    }
                }
            }
        } else {
            #pragma unroll
            for (int mf = 0; mf < 2; ++mf) {
                #pragma unroll
                for (int r = 0; r < 4; ++r) {
                    int row = rowbase + mf * 16 + sub * 4 + r;
                    int a = row / 72;
                    int b = row - a * 72 + half * 72;
                    int ab16i = (a * 144 + b) * 16;
                    #pragma unroll
                    for (int nf = 0; nf < 8; ++nf) {
                        int pq = (TERM == 0) ? (nf * 2654208 + XF * 331776)
                                             : (XF * 2654208 + nf * 331776);
                        int idx = pq + ab16i + lr;
                        if (TERM == 0) out[idx] = acc[mf][nf][r];
                        else           out[idx] += acc[mf][nf][r];
                    }
                }
            }
        }
    }   // tile loop
#undef STAGE_B
#undef LOAD_A
#undef CHUNK_BARRIER
}

extern "C" void kernel_launch(void* const* d_in, const int* in_sizes, int n_in,
                              void* d_out, int out_size, void* d_ws, size_t ws_size,
                              hipStream_t stream) {
    const float* nodal = (const float*)d_in[0];
    const float* coef0 = (const float*)d_in[1];
    const float* coef1 = (const float*)d_in[2];
    const float* ws0   = (const float*)d_in[3];
    const float* ws1   = (const float*)d_in[4];
    const float* grid  = (const float*)d_in[5];
    float* outp = (float*)d_out;

    unsigned short* B      = (unsigned short*)d_ws;
    unsigned short* nodalb = (unsigned short*)((char*)d_ws + NB_OFF);
    unsigned short* c0     = (unsigned short*)((char*)d_ws + C0_OFF);
    const bool ab16 = ws_size >= (size_t)NB_OFF + (size_t)NODAL_ELEMS * 2;
    const bool c0b  = ws_size >= C0_OFF + (size_t)NODAL_ELEMS * 2;

    hipLaunchKernelGGL(build_b_kernel, dim3(640), dim3(256), 0, stream,
                       coef0, coef1, ws0, ws1, grid, B);
    if (ab16)
        hipLaunchKernelGGL(cvt_kernel, dim3(2048), dim3(256), 0, stream,
                           nodal, nodalb, NODAL_ELEMS / 4);

    dim3 g(648);
    if (ab16 && c0b) {
        hipLaunchKernelGGL((conv_mfma<0, true, true>), g, dim3(256), 0, stream,
                           nodal, nodalb, B, c0, outp);
        hipLaunchKernelGGL((conv_mfma<1, true, true>), g, dim3(256), 0, stream,
                           nodal, nodalb, B + BSLAB, c0, outp);
    } else if (ab16) {
        hipLaunchKernelGGL((conv_mfma<0, true, false>), g, dim3(256), 0, stream,
                           nodal, nodalb, B, c0, outp);
        hipLaunchKernelGGL((conv_mfma<1, true, false>), g, dim3(256), 0, stream,
                           nodal, nodalb, B + BSLAB, c0, outp);
    } else {
        hipLaunchKernelGGL((conv_mfma<0, false, false>), g, dim3(256), 0, stream,
                           nodal, nodalb, B, c0, outp);
        hipLaunchKernelGGL((conv_mfma<1, false, false>), g, dim3(256), 0, stream,
                           nodal, nodalb, B + BSLAB, c0, outp);
    }
}

// Round 13
// 103.355 us; speedup vs baseline: 1.6421x; 1.6421x over previous
//
#include <hip/hip_runtime.h>

typedef __attribute__((ext_vector_type(8))) short short8;
typedef __attribute__((ext_vector_type(4))) float f32x4;

#define NODAL_ELEMS 21233664     // 8*8*144*144*16
#define BSLAB 81920              // 640*128 elements per direction
#define NB_OFF 327680            // byte offset of bf16 nodal in ws (2*BSLAB*2)
#define C0_OFF (NB_OFF + (size_t)NODAL_ELEMS * 2)   // bf16 C0 partial (frag order)

__device__ __forceinline__ unsigned short f2bf(float f) {
    unsigned int u = __float_as_uint(f);
    u += 0x7FFFu + ((u >> 16) & 1u);     // RNE
    return (unsigned short)(u >> 16);
}
__device__ __forceinline__ float bf2f(unsigned short s) {
    return __uint_as_float(((unsigned int)s) << 16);
}

__device__ __forceinline__ void gload_lds16(const void* g, void* l) {
    __builtin_amdgcn_global_load_lds(
        (const __attribute__((address_space(1))) unsigned int*)g,
        (__attribute__((address_space(3))) unsigned int*)l, 16, 0, 0);
}

// ---------------------------------------------------------------------------
// Fused prep kernel. Blocks 0..639: build B matrices in fragment order
// B[d][kk=K/8][n][j=K%8]. Blocks 640..2687: nodal fp32 -> bf16 (grid-stride).
// The two halves are independent; fusing saves one dispatch ramp.
// ---------------------------------------------------------------------------
__global__ void prep_kernel(const float* __restrict__ coef0,
                            const float* __restrict__ coef1,
                            const float* __restrict__ ws0,
                            const float* __restrict__ ws1,
                            const float* __restrict__ grid,
                            unsigned short* __restrict__ B,
                            const float* __restrict__ nodal,
                            unsigned short* __restrict__ nodalb,
                            int do_cvt)
{
    const int blk = blockIdx.x;
    if (blk < 640) {
        // ---- build B ----
        const int d   = (blk >= 320) ? 1 : 0;
        const int rem = blk - d * 320;
        const int k   = rem >> 6;
        const int X   = (rem >> 3) & 7;
        const int x   = rem & 7;

        const float* __restrict__ coef = d ? coef1 : coef0;
        const float* __restrict__ ws   = d ? ws1 : ws0;
        unsigned short* __restrict__ Bd = B + d * BSLAB;

        const float xy = (grid[X] - (grid[x] + (float)(k - 2))) * 0.25f;
        const int t = threadIdx.x;          // i*16 + o
        const int i = t >> 4;
        const int o = t & 15;

        float acc = 0.f;
        #pragma unroll 1
        for (int j = 0; j < 33; ++j) {
            float ang = 6.283185307179586f * (float)j * xy;
            float c = cosf(ang);
            float s = sinf(ang);
            float sc = (j == 0 || j == 32) ? 1.f : 2.f;
            float rr = coef[j * 256 + t];
            float ii = (j >= 1 && j <= 31) ? coef[(64 - j) * 256 + t] : 0.f;
            acc += sc * (c * rr - s * ii);
        }
        float val = acc * ws[(k * 8 + X) * 8 + x];

        const int kk = k * 16 + x * 2 + (i >> 3);
        const int jj = i & 7;
        const int n  = X * 16 + o;
        Bd[(kk * 128 + n) * 8 + jj] = f2bf(val);
    } else if (do_cvt) {
        // ---- nodal fp32 -> bf16 ----
        const int n4 = NODAL_ELEMS / 4;
        int idx = (blk - 640) * blockDim.x + threadIdx.x;
        int stride = (gridDim.x - 640) * blockDim.x;
        for (int j = idx; j < n4; j += stride) {
            float4 v = ((const float4*)nodal)[j];
            ushort4 r;
            r.x = f2bf(v.x); r.y = f2bf(v.y); r.z = f2bf(v.z); r.w = f2bf(v.w);
            ((ushort4*)nodalb)[j] = r;
        }
    }
}

// ---------------------------------------------------------------------------
// MFMA conv kernel. TERM=0: fixed q, contract (k,x,i); writes C0 in
// accumulator-FRAGMENT order keyed by (rest,w,mf,p,q,lane). TERM=1: fixed p,
// contract (k,y,i); adds C0 + writes fp32 out (or RMW fp32 fallback).
// Block: 256 thr (4 waves). Tile: M=128 (wave M32xN128), N=128, K=640.
// K-loop: 10 chunks of 2 K-steps. Depth-2 pipeline: B staged into a 3x16KB
// LDS ring via global_load_lds 2 chunks ahead; A reg-prefetched 2 chunks
// ahead. Barrier = counted s_waitcnt vmcnt + raw s_barrier (no drain).
// Grid 1296 1-D, XCD-pinned (XF=bid&7) + b-halves for L2 locality.
// ---------------------------------------------------------------------------
template<int TERM, bool AB16, bool C0B16>
__global__ __launch_bounds__(256, 3)
void conv_mfma(const float* __restrict__ nodalf,
               const unsigned short* __restrict__ nodalb,
               const unsigned short* __restrict__ Bmat,
               unsigned short* __restrict__ c0,
               float* __restrict__ out)
{
    __shared__ __align__(16) char lds[3][16384];   // 3 x 16KB B-chunk ring

    const int tid = threadIdx.x;
    const int w   = tid >> 6;
    const int l   = tid & 63;
    const int sub = l >> 4;
    const int lr  = l & 15;

    const int bid  = blockIdx.x;
    const int XF   = bid & 7;           // q (TERM0) / p (TERM1) -> per-XCD slab
    const int rest = bid >> 3;          // 0..161
    const int half = (rest >= 81) ? 1 : 0;
    const int mt   = rest - half * 81;  // 0..80

    const int scal = (TERM == 0) ? XF * 331776 : XF * 2654208;
    const int KSTR = (TERM == 0) ? 2654208 : 331776;   // x / y stride (elems)

    // per-lane per-tap base element offsets (incl. lane K-sub placement)
    int base[2][5];
    const int rowbase = mt * 128 + w * 32;
    #pragma unroll
    for (int mf = 0; mf < 2; ++mf) {
        int row = rowbase + mf * 16 + lr;      // 0..10367
        int a = row / 72;
        int b = row - a * 72 + half * 72;
        #pragma unroll
        for (int k = 0; k < 5; ++k) {
            int sh = ((TERM == 0) ? a : b) + k - 2;
            if (sh < 0) sh += 144;
            if (sh >= 144) sh -= 144;
            int off = (TERM == 0) ? (sh * 2304 + b * 16) : (a * 2304 + sh * 16);
            base[mf][k] = off + (sub >> 1) * KSTR + (sub & 1) * 8;
        }
    }

    const unsigned short* nb = nodalb + scal;
    const float* nfp = nodalf + scal;
    const char* Bb = (const char*)Bmat;

    f32x4 acc[2][8];
    #pragma unroll
    for (int mf = 0; mf < 2; ++mf)
        #pragma unroll
        for (int nf = 0; nf < 8; ++nf)
            acc[mf][nf] = (f32x4){0.f, 0.f, 0.f, 0.f};

    short8 Ab[3][2][2];        // [slot][ksp][mf] bf16 path
    float4 Af[3][2][2][2];     // fp32 fallback path

#define STAGE_B(buf_, c_) do {                                               \
    _Pragma("unroll")                                                        \
    for (int u_ = 0; u_ < 4; ++u_)                                           \
        gload_lds16(Bb + (c_) * 16384 + u_ * 4096 + tid * 16,                \
                    &lds[buf_][u_ * 4096 + tid * 16]);                       \
} while (0)

#define LOAD_A(slot_, c_) do {                                               \
    _Pragma("unroll")                                                        \
    for (int ksp_ = 0; ksp_ < 2; ++ksp_) {                                   \
        const int ks_ = 2 * (c_) + ksp_;                                     \
        _Pragma("unroll")                                                    \
        for (int mf_ = 0; mf_ < 2; ++mf_) {                                  \
            if (AB16) {                                                      \
                Ab[slot_][ksp_][mf_] = *(const short8*)                      \
                    (nb + base[mf_][ks_ >> 2] + (ks_ & 3) * 2 * KSTR);       \
            } else {                                                         \
                const float* s_ = nfp + base[mf_][ks_ >> 2]                  \
                                      + (ks_ & 3) * 2 * KSTR;                \
                Af[slot_][ksp_][mf_][0] = *(const float4*)s_;                \
                Af[slot_][ksp_][mf_][1] = *(const float4*)(s_ + 4);          \
            }                                                                \
        }                                                                    \
    } } while (0)

// counted-vmcnt barrier: allow vm_ newest ops outstanding; everything older
// is retired before s_barrier. No vmcnt(0) drain anywhere in the loop.
#define CHUNK_BARRIER(vm_) do {                                              \
    __builtin_amdgcn_sched_barrier(0);                                       \
    asm volatile("s_waitcnt vmcnt(" vm_ ")" ::: "memory");                   \
    __builtin_amdgcn_s_barrier();                                            \
    __builtin_amdgcn_sched_barrier(0);                                       \
} while (0)

    // prologue: stage chunks 0,1 ; A-load chunks 0,1
    STAGE_B(0, 0);
    STAGE_B(1, 1);
    __builtin_amdgcn_sched_barrier(0);
    LOAD_A(0, 0);
    LOAD_A(1, 1);
    CHUNK_BARRIER("8");     // retires S0,S1 (A0/A1 waited by use-deps)

    #pragma unroll
    for (int c = 0; c < 10; ++c) {
        if (c < 8) {
            STAGE_B((c + 2) % 3, c + 2);
            __builtin_amdgcn_sched_barrier(0);
            LOAD_A((c + 2) % 3, c + 2);
            __builtin_amdgcn_sched_barrier(0);
        }

        #pragma unroll
        for (int ksp = 0; ksp < 2; ++ksp) {
            short8 a0, a1;
            if (AB16) {
                a0 = Ab[c % 3][ksp][0];
                a1 = Ab[c % 3][ksp][1];
            } else {
                #pragma unroll
                for (int e = 0; e < 4; ++e) {
                    a0[e]     = (short)f2bf(((const float*)&Af[c % 3][ksp][0][0])[e]);
                    a0[e + 4] = (short)f2bf(((const float*)&Af[c % 3][ksp][0][1])[e]);
                    a1[e]     = (short)f2bf(((const float*)&Af[c % 3][ksp][1][0])[e]);
                    a1[e + 4] = (short)f2bf(((const float*)&Af[c % 3][ksp][1][1])[e]);
                }
            }

            const char* bbase = lds[c % 3] + ksp * 8192 + sub * 2048 + lr * 16;
            #pragma unroll
            for (int nf = 0; nf < 8; ++nf) {
                short8 bf = *(const short8*)(bbase + nf * 256);
                acc[0][nf] = __builtin_amdgcn_mfma_f32_16x16x32_bf16(
                    a0, bf, acc[0][nf], 0, 0, 0);
                acc[1][nf] = __builtin_amdgcn_mfma_f32_16x16x32_bf16(
                    a1, bf, acc[1][nf], 0, 0, 0);
            }
        }

        if (c < 9) {
            if (c == 8) CHUNK_BARRIER("4");   // newest 4 = A(9); S(9) retired
            else        CHUNK_BARRIER("8");
        }
    }

    // ---- epilogue ----
    if (C0B16) {
        // C0 fragment key symmetric in (p,q): frag(rest,w,mf,p,q), 256 elems
        // TERM0: p = nf (N-dim), q = XF.  TERM1: p = XF, q = nf.
        #pragma unroll
        for (int mf = 0; mf < 2; ++mf) {
            #pragma unroll
            for (int nf = 0; nf < 8; ++nf) {
                const int P = (TERM == 0) ? nf : XF;
                const int Q = (TERM == 0) ? XF : nf;
                unsigned short* cp = c0 +
                    (((((size_t)rest * 4 + w) * 2 + mf) * 8 + P) * 8 + Q) * 256
                    + l * 4;
                if (TERM == 0) {
                    ushort4 cs;
                    cs.x = f2bf(acc[mf][nf][0]);
                    cs.y = f2bf(acc[mf][nf][1]);
                    cs.z = f2bf(acc[mf][nf][2]);
                    cs.w = f2bf(acc[mf][nf][3]);
                    *(ushort4*)cp = cs;
                } else {
                    ushort4 cv = *(const ushort4*)cp;
                    unsigned short ca[4] = {cv.x, cv.y, cv.z, cv.w};
                    #pragma unroll
                    for (int r = 0; r < 4; ++r) {
                        int row = rowbase + mf * 16 + sub * 4 + r;
                        int a = row / 72;
                        int b = row - a * 72 + half * 72;
                        int idx = XF * 2654208 + nf * 331776 +
                                  (a * 144 + b) * 16 + lr;
                        out[idx] = acc[mf][nf][r] + bf2f(ca[r]);
                    }
                }
            }
        }
    } else {
        #pragma unroll
        for (int mf = 0; mf < 2; ++mf) {
            #pragma unroll
            for (int r = 0; r < 4; ++r) {
                int row = rowbase + mf * 16 + sub * 4 + r;
                int a = row / 72;
                int b = row - a * 72 + half * 72;
                int ab16i = (a * 144 + b) * 16;
                #pragma unroll
                for (int nf = 0; nf < 8; ++nf) {
                    int pq = (TERM == 0) ? (nf * 2654208 + XF * 331776)
                                         : (XF * 2654208 + nf * 331776);
                    int idx = pq + ab16i + lr;
                    if (TERM == 0) out[idx] = acc[mf][nf][r];
                    else           out[idx] += acc[mf][nf][r];
                }
            }
        }
    }
#undef STAGE_B
#undef LOAD_A
#undef CHUNK_BARRIER
}

extern "C" void kernel_launch(void* const* d_in, const int* in_sizes, int n_in,
                              void* d_out, int out_size, void* d_ws, size_t ws_size,
                              hipStream_t stream) {
    const float* nodal = (const float*)d_in[0];
    const float* coef0 = (const float*)d_in[1];
    const float* coef1 = (const float*)d_in[2];
    const float* ws0   = (const float*)d_in[3];
    const float* ws1   = (const float*)d_in[4];
    const float* grid  = (const float*)d_in[5];
    float* outp = (float*)d_out;

    unsigned short* B      = (unsigned short*)d_ws;
    unsigned short* nodalb = (unsigned short*)((char*)d_ws + NB_OFF);
    unsigned short* c0     = (unsigned short*)((char*)d_ws + C0_OFF);
    const bool ab16 = ws_size >= (size_t)NB_OFF + (size_t)NODAL_ELEMS * 2;
    const bool c0b  = ws_size >= C0_OFF + (size_t)NODAL_ELEMS * 2;

    hipLaunchKernelGGL(prep_kernel, dim3(2688), dim3(256), 0, stream,
                       coef0, coef1, ws0, ws1, grid, B,
                       nodal, nodalb, ab16 ? 1 : 0);

    dim3 g(1296);
    if (ab16 && c0b) {
        hipLaunchKernelGGL((conv_mfma<0, true, true>), g, dim3(256), 0, stream,
                           nodal, nodalb, B, c0, outp);
        hipLaunchKernelGGL((conv_mfma<1, true, true>), g, dim3(256), 0, stream,
                           nodal, nodalb, B + BSLAB, c0, outp);
    } else if (ab16) {
        hipLaunchKernelGGL((conv_mfma<0, true, false>), g, dim3(256), 0, stream,
                           nodal, nodalb, B, c0, outp);
        hipLaunchKernelGGL((conv_mfma<1, true, false>), g, dim3(256), 0, stream,
                           nodal, nodalb, B + BSLAB, c0, outp);
    } else {
        hipLaunchKernelGGL((conv_mfma<0, false, false>), g, dim3(256), 0, stream,
                           nodal, nodalb, B, c0, outp);
        hipLaunchKernelGGL((conv_mfma<1, false, false>), g, dim3(256), 0, stream,
                           nodal, nodalb, B + BSLAB, c0, outp);
    }
}

// Round 14
// 102.735 us; speedup vs baseline: 1.6520x; 1.0060x over previous
//
#include <hip/hip_runtime.h>

typedef __attribute__((ext_vector_type(8))) short short8;
typedef __attribute__((ext_vector_type(4))) float f32x4;

#define NODAL_ELEMS 21233664     // 8*8*144*144*16
#define BSLAB 81920              // 640*128 elements per direction
#define NB_OFF 327680            // byte offset of bf16 nodal in ws (2*BSLAB*2)
#define C0_OFF (NB_OFF + (size_t)NODAL_ELEMS * 2)   // bf16 C0 partial (frag order)

__device__ __forceinline__ unsigned short f2bf(float f) {
    unsigned int u = __float_as_uint(f);
    u += 0x7FFFu + ((u >> 16) & 1u);     // RNE
    return (unsigned short)(u >> 16);
}
__device__ __forceinline__ float bf2f(unsigned short s) {
    return __uint_as_float(((unsigned int)s) << 16);
}

__device__ __forceinline__ void gload_lds16(const void* g, void* l) {
    __builtin_amdgcn_global_load_lds(
        (const __attribute__((address_space(1))) unsigned int*)g,
        (__attribute__((address_space(3))) unsigned int*)l, 16, 0, 0);
}

// ---------------------------------------------------------------------------
// Fused prep kernel. Blocks 0..639: build B matrices in fragment order
// B[d][kk=K/8][n][j=K%8]. Blocks 640..2687: nodal fp32 -> bf16 (grid-stride).
// ---------------------------------------------------------------------------
__global__ void prep_kernel(const float* __restrict__ coef0,
                            const float* __restrict__ coef1,
                            const float* __restrict__ ws0,
                            const float* __restrict__ ws1,
                            const float* __restrict__ grid,
                            unsigned short* __restrict__ B,
                            const float* __restrict__ nodal,
                            unsigned short* __restrict__ nodalb,
                            int do_cvt)
{
    const int blk = blockIdx.x;
    if (blk < 640) {
        const int d   = (blk >= 320) ? 1 : 0;
        const int rem = blk - d * 320;
        const int k   = rem >> 6;
        const int X   = (rem >> 3) & 7;
        const int x   = rem & 7;

        const float* __restrict__ coef = d ? coef1 : coef0;
        const float* __restrict__ ws   = d ? ws1 : ws0;
        unsigned short* __restrict__ Bd = B + d * BSLAB;

        const float xy = (grid[X] - (grid[x] + (float)(k - 2))) * 0.25f;
        const int t = threadIdx.x;          // i*16 + o
        const int i = t >> 4;
        const int o = t & 15;

        float acc = 0.f;
        #pragma unroll 1
        for (int j = 0; j < 33; ++j) {
            float ang = 6.283185307179586f * (float)j * xy;
            float c = cosf(ang);
            float s = sinf(ang);
            float sc = (j == 0 || j == 32) ? 1.f : 2.f;
            float rr = coef[j * 256 + t];
            float ii = (j >= 1 && j <= 31) ? coef[(64 - j) * 256 + t] : 0.f;
            acc += sc * (c * rr - s * ii);
        }
        float val = acc * ws[(k * 8 + X) * 8 + x];

        const int kk = k * 16 + x * 2 + (i >> 3);
        const int jj = i & 7;
        const int n  = X * 16 + o;
        Bd[(kk * 128 + n) * 8 + jj] = f2bf(val);
    } else if (do_cvt) {
        const int n4 = NODAL_ELEMS / 4;
        int idx = (blk - 640) * blockDim.x + threadIdx.x;
        int stride = (gridDim.x - 640) * blockDim.x;
        for (int j = idx; j < n4; j += stride) {
            float4 v = ((const float4*)nodal)[j];
            ushort4 r;
            r.x = f2bf(v.x); r.y = f2bf(v.y); r.z = f2bf(v.z); r.w = f2bf(v.w);
            ((ushort4*)nodalb)[j] = r;
        }
    }
}

// ---------------------------------------------------------------------------
// MFMA conv kernel. TERM=0: fixed q, contract (k,x,i); writes C0 in
// accumulator-FRAGMENT order keyed by (rest,w,mf,p,q,lane). TERM=1: fixed p,
// contract (k,y,i); adds C0 + writes fp32 out (or RMW fp32 fallback).
// Block: 256 thr (4 waves). Tile: M=128 (wave M32xN128), N=128, K=640.
// K-loop: 10 chunks of 2 K-steps. Depth-2 pipeline: B staged into a 3x16KB
// LDS ring via global_load_lds 2 chunks ahead; A reg-prefetched 2 chunks
// ahead. Steady barrier = s_waitcnt vmcnt(12) + raw s_barrier: retires only
// S(c+1) (needed by next body's ds_reads); A(c+1) stays in flight — its
// retirement is enforced by the compiler's use-dep wait a chunk later
// (m135: vmcnt retires oldest-first). Prologue vmcnt(8): retires S0,S1,
// keeps A0,A1. c==8 barrier vmcnt(4): retires S(9), keeps A(9).
// Grid 1296 1-D, XCD-pinned (XF=bid&7) + b-halves for L2 locality.
// ---------------------------------------------------------------------------
template<int TERM, bool AB16, bool C0B16>
__global__ __launch_bounds__(256, 3)
void conv_mfma(const float* __restrict__ nodalf,
               const unsigned short* __restrict__ nodalb,
               const unsigned short* __restrict__ Bmat,
               unsigned short* __restrict__ c0,
               float* __restrict__ out)
{
    __shared__ __align__(16) char lds[3][16384];   // 3 x 16KB B-chunk ring

    const int tid = threadIdx.x;
    const int w   = tid >> 6;
    const int l   = tid & 63;
    const int sub = l >> 4;
    const int lr  = l & 15;

    const int bid  = blockIdx.x;
    const int XF   = bid & 7;           // q (TERM0) / p (TERM1) -> per-XCD slab
    const int rest = bid >> 3;          // 0..161
    const int half = (rest >= 81) ? 1 : 0;
    const int mt   = rest - half * 81;  // 0..80

    const int scal = (TERM == 0) ? XF * 331776 : XF * 2654208;
    const int KSTR = (TERM == 0) ? 2654208 : 331776;   // x / y stride (elems)

    // per-lane per-tap base element offsets (incl. lane K-sub placement)
    int base[2][5];
    const int rowbase = mt * 128 + w * 32;
    #pragma unroll
    for (int mf = 0; mf < 2; ++mf) {
        int row = rowbase + mf * 16 + lr;      // 0..10367
        int a = row / 72;
        int b = row - a * 72 + half * 72;
        #pragma unroll
        for (int k = 0; k < 5; ++k) {
            int sh = ((TERM == 0) ? a : b) + k - 2;
            if (sh < 0) sh += 144;
            if (sh >= 144) sh -= 144;
            int off = (TERM == 0) ? (sh * 2304 + b * 16) : (a * 2304 + sh * 16);
            base[mf][k] = off + (sub >> 1) * KSTR + (sub & 1) * 8;
        }
    }

    const unsigned short* nb = nodalb + scal;
    const float* nfp = nodalf + scal;
    const char* Bb = (const char*)Bmat;

    f32x4 acc[2][8];
    #pragma unroll
    for (int mf = 0; mf < 2; ++mf)
        #pragma unroll
        for (int nf = 0; nf < 8; ++nf)
            acc[mf][nf] = (f32x4){0.f, 0.f, 0.f, 0.f};

    short8 Ab[3][2][2];        // [slot][ksp][mf] bf16 path
    float4 Af[3][2][2][2];     // fp32 fallback path

#define STAGE_B(buf_, c_) do {                                               \
    _Pragma("unroll")                                                        \
    for (int u_ = 0; u_ < 4; ++u_)                                           \
        gload_lds16(Bb + (c_) * 16384 + u_ * 4096 + tid * 16,                \
                    &lds[buf_][u_ * 4096 + tid * 16]);                       \
} while (0)

#define LOAD_A(slot_, c_) do {                                               \
    _Pragma("unroll")                                                        \
    for (int ksp_ = 0; ksp_ < 2; ++ksp_) {                                   \
        const int ks_ = 2 * (c_) + ksp_;                                     \
        _Pragma("unroll")                                                    \
        for (int mf_ = 0; mf_ < 2; ++mf_) {                                  \
            if (AB16) {                                                      \
                Ab[slot_][ksp_][mf_] = *(const short8*)                      \
                    (nb + base[mf_][ks_ >> 2] + (ks_ & 3) * 2 * KSTR);       \
            } else {                                                         \
                const float* s_ = nfp + base[mf_][ks_ >> 2]                  \
                                      + (ks_ & 3) * 2 * KSTR;                \
                Af[slot_][ksp_][mf_][0] = *(const float4*)s_;                \
                Af[slot_][ksp_][mf_][1] = *(const float4*)(s_ + 4);          \
            }                                                                \
        }                                                                    \
    } } while (0)

// counted-vmcnt barrier: allow vm_ newest ops outstanding; everything older
// is retired before s_barrier. No vmcnt(0) drain anywhere in the loop.
#define CHUNK_BARRIER(vm_) do {                                              \
    __builtin_amdgcn_sched_barrier(0);                                       \
    asm volatile("s_waitcnt vmcnt(" vm_ ")" ::: "memory");                   \
    __builtin_amdgcn_s_barrier();                                            \
    __builtin_amdgcn_sched_barrier(0);                                       \
} while (0)

    // prologue: stage chunks 0,1 ; A-load chunks 0,1
    STAGE_B(0, 0);
    STAGE_B(1, 1);
    __builtin_amdgcn_sched_barrier(0);
    LOAD_A(0, 0);
    LOAD_A(1, 1);
    CHUNK_BARRIER("8");     // retires S0,S1; A0,A1 stay in flight

    #pragma unroll
    for (int c = 0; c < 10; ++c) {
        if (c < 8) {
            STAGE_B((c + 2) % 3, c + 2);
            __builtin_amdgcn_sched_barrier(0);
            LOAD_A((c + 2) % 3, c + 2);
            __builtin_amdgcn_sched_barrier(0);
        }

        #pragma unroll
        for (int ksp = 0; ksp < 2; ++ksp) {
            short8 a0, a1;
            if (AB16) {
                a0 = Ab[c % 3][ksp][0];
                a1 = Ab[c % 3][ksp][1];
            } else {
                #pragma unroll
                for (int e = 0; e < 4; ++e) {
                    a0[e]     = (short)f2bf(((const float*)&Af[c % 3][ksp][0][0])[e]);
                    a0[e + 4] = (short)f2bf(((const float*)&Af[c % 3][ksp][0][1])[e]);
                    a1[e]     = (short)f2bf(((const float*)&Af[c % 3][ksp][1][0])[e]);
                    a1[e + 4] = (short)f2bf(((const float*)&Af[c % 3][ksp][1][1])[e]);
                }
            }

            const char* bbase = lds[c % 3] + ksp * 8192 + sub * 2048 + lr * 16;
            #pragma unroll
            for (int nf = 0; nf < 8; ++nf) {
                short8 bf = *(const short8*)(bbase + nf * 256);
                acc[0][nf] = __builtin_amdgcn_mfma_f32_16x16x32_bf16(
                    a0, bf, acc[0][nf], 0, 0, 0);
                acc[1][nf] = __builtin_amdgcn_mfma_f32_16x16x32_bf16(
                    a1, bf, acc[1][nf], 0, 0, 0);
            }
        }

        if (c < 9) {
            if (c == 8) CHUNK_BARRIER("4");    // retires S(9); A(9) in flight
            else        CHUNK_BARRIER("12");   // retires S(c+1) ONLY
        }
    }

    // ---- epilogue ----
    if (C0B16) {
        // C0 fragment key symmetric in (p,q): frag(rest,w,mf,p,q), 256 elems
        // TERM0: p = nf (N-dim), q = XF.  TERM1: p = XF, q = nf.
        #pragma unroll
        for (int mf = 0; mf < 2; ++mf) {
            #pragma unroll
            for (int nf = 0; nf < 8; ++nf) {
                const int P = (TERM == 0) ? nf : XF;
                const int Q = (TERM == 0) ? XF : nf;
                unsigned short* cp = c0 +
                    (((((size_t)rest * 4 + w) * 2 + mf) * 8 + P) * 8 + Q) * 256
                    + l * 4;
                if (TERM == 0) {
                    ushort4 cs;
                    cs.x = f2bf(acc[mf][nf][0]);
                    cs.y = f2bf(acc[mf][nf][1]);
                    cs.z = f2bf(acc[mf][nf][2]);
                    cs.w = f2bf(acc[mf][nf][3]);
                    *(ushort4*)cp = cs;
                } else {
                    ushort4 cv = *(const ushort4*)cp;
                    unsigned short ca[4] = {cv.x, cv.y, cv.z, cv.w};
                    #pragma unroll
                    for (int r = 0; r < 4; ++r) {
                        int row = rowbase + mf * 16 + sub * 4 + r;
                        int a = row / 72;
                        int b = row - a * 72 + half * 72;
                        int idx = XF * 2654208 + nf * 331776 +
                                  (a * 144 + b) * 16 + lr;
                        out[idx] = acc[mf][nf][r] + bf2f(ca[r]);
                    }
                }
            }
        }
    } else {
        #pragma unroll
        for (int mf = 0; mf < 2; ++mf) {
            #pragma unroll
            for (int r = 0; r < 4; ++r) {
                int row = rowbase + mf * 16 + sub * 4 + r;
                int a = row / 72;
                int b = row - a * 72 + half * 72;
                int ab16i = (a * 144 + b) * 16;
                #pragma unroll
                for (int nf = 0; nf < 8; ++nf) {
                    int pq = (TERM == 0) ? (nf * 2654208 + XF * 331776)
                                         : (XF * 2654208 + nf * 331776);
                    int idx = pq + ab16i + lr;
                    if (TERM == 0) out[idx] = acc[mf][nf][r];
                    else           out[idx] += acc[mf][nf][r];
                }
            }
        }
    }
#undef STAGE_B
#undef LOAD_A
#undef CHUNK_BARRIER
}

extern "C" void kernel_launch(void* const* d_in, const int* in_sizes, int n_in,
                              void* d_out, int out_size, void* d_ws, size_t ws_size,
                              hipStream_t stream) {
    const float* nodal = (const float*)d_in[0];
    const float* coef0 = (const float*)d_in[1];
    const float* coef1 = (const float*)d_in[2];
    const float* ws0   = (const float*)d_in[3];
    const float* ws1   = (const float*)d_in[4];
    const float* grid  = (const float*)d_in[5];
    float* outp = (float*)d_out;

    unsigned short* B      = (unsigned short*)d_ws;
    unsigned short* nodalb = (unsigned short*)((char*)d_ws + NB_OFF);
    unsigned short* c0     = (unsigned short*)((char*)d_ws + C0_OFF);
    const bool ab16 = ws_size >= (size_t)NB_OFF + (size_t)NODAL_ELEMS * 2;
    const bool c0b  = ws_size >= C0_OFF + (size_t)NODAL_ELEMS * 2;

    hipLaunchKernelGGL(prep_kernel, dim3(2688), dim3(256), 0, stream,
                       coef0, coef1, ws0, ws1, grid, B,
                       nodal, nodalb, ab16 ? 1 : 0);

    dim3 g(1296);
    if (ab16 && c0b) {
        hipLaunchKernelGGL((conv_mfma<0, true, true>), g, dim3(256), 0, stream,
                           nodal, nodalb, B, c0, outp);
        hipLaunchKernelGGL((conv_mfma<1, true, true>), g, dim3(256), 0, stream,
                           nodal, nodalb, B + BSLAB, c0, outp);
    } else if (ab16) {
        hipLaunchKernelGGL((conv_mfma<0, true, false>), g, dim3(256), 0, stream,
                           nodal, nodalb, B, c0, outp);
        hipLaunchKernelGGL((conv_mfma<1, true, false>), g, dim3(256), 0, stream,
                           nodal, nodalb, B + BSLAB, c0, outp);
    } else {
        hipLaunchKernelGGL((conv_mfma<0, false, false>), g, dim3(256), 0, stream,
                           nodal, nodalb, B, c0, outp);
        hipLaunchKernelGGL((conv_mfma<1, false, false>), g, dim3(256), 0, stream,
                           nodal, nodalb, B + BSLAB, c0, outp);
    }
}